// Round 8
// baseline (236.912 us; speedup 1.0000x reference)
//
#include <hip/hip_runtime.h>
#include <math.h>

// OHNM loss: pos BCE sum + top-k(600000) negative softplus sum, mean over 800000.
//
// R8: 4 dispatches (was 6). Zero contended RMWs (R1/R4/R5/R6 lesson: ~7ns per
// same-line device RMW). Two-level radix over kp = key-K0 (< 2^26 for x in
// [1,256)): L1 = kp>>13 (8192 bins), L2 = kp & 0x1FFF -> L2 bin FULLY
// determines the key, so per-bin float softplus sums (histF2) finish the job
// with no extra pass.
//   k_main: stream x,y (67MB); pos partial sums; per-WAVE private cand
//           regions (ballot-cursor, plain stores); cnt/posp/maxk slot stores;
//           block 0 zeroes hist2/histF2.
//   k_hist: 32 private 8192-bin partial hists (pure stores, no merge).
//   k_mid:  per-block re-derive hard+counts; in-block scan of partials ->
//           (b1,r1); sure-sum (bin>b1); boundary bin (~1.1K keys) ->
//           scattered hist2/histF2 atomics. Stores b1,r1 + sure partials.
//   k_fin:  1 block: scan hist2 -> (b2,r2); total = pos + sure +
//           sum(histF2 above b2) + r2*softplus(H); out = total/(4p).
// hard mode (count shortfall / region overflow / x>=256): coarse bins
// k>>19 / (k>>6)&0x1FFF re-streamed from x,y; k_fin resolves the last 6 bits
// with a single-block stream + 64-bin LDS hist. Exact for ANY input; never
// triggered for this one.

#define K0 0xBF800000u             // f2key(1.0f)
#define FINE_LIMIT 0xC3800000u     // f2key(256.0f) = K0 + 2^26
#define NWAVES 8192                // k_main: 2048 blocks x 4 waves
#define REG 256                    // cand words per wave (lambda=159, +7.7sigma)
#define NH 32                      // partial-hist blocks
#define NB1 8192
#define NB2 8192

// ---- ws layout (word offsets) ----
#define CTRL_W   16640
#define OFF_H1P  (CTRL_W)                    // 32 x 8192 partials
#define OFF_CNT  (OFF_H1P + NH * NB1)        // 8192 per-wave counts (|ovf<<31)
#define OFF_POSP (OFF_CNT + NWAVES)          // 8192 floats
#define OFF_MAXK (OFF_POSP + NWAVES)         // 8192
#define OFF_SURE (OFF_MAXK + NWAVES)         // 32 floats (pad 64)
#define OFF_CAND (OFF_SURE + 64)
#define CANDW    (NWAVES * REG)              // 2,097,152 words (8 MB)

struct Ctrl {
    unsigned hist2[NB2];
    float    histF2[NB2];
    unsigned b1, r1;
};

__device__ __forceinline__ unsigned f2key(float x) {
    unsigned u = __float_as_uint(x);
    return (u & 0x80000000u) ? ~u : (u | 0x80000000u);
}
__device__ __forceinline__ float key2f(unsigned k) {
    unsigned u = (k & 0x80000000u) ? (k & 0x7FFFFFFFu) : ~k;
    return __uint_as_float(u);
}
__device__ __forceinline__ float softplusf(float x) {
    return fmaxf(x, 0.0f) + __logf(1.0f + __expf(-fabsf(x)));
}
__device__ __forceinline__ float wred(float v) {
    v += __shfl_down(v, 32); v += __shfl_down(v, 16); v += __shfl_down(v, 8);
    v += __shfl_down(v, 4);  v += __shfl_down(v, 2);  v += __shfl_down(v, 1);
    return v;
}
__device__ __forceinline__ unsigned wredmax(unsigned v) {
    v = max(v, (unsigned)__shfl_down((int)v, 32));
    v = max(v, (unsigned)__shfl_down((int)v, 16));
    v = max(v, (unsigned)__shfl_down((int)v, 8));
    v = max(v, (unsigned)__shfl_down((int)v, 4));
    v = max(v, (unsigned)__shfl_down((int)v, 2));
    v = max(v, (unsigned)__shfl_down((int)v, 1));
    return v;
}
// block float-sum; result valid on thread 0
__device__ float bred(float v) {
    __shared__ float sb[16];
    const int lane = threadIdx.x & 63, w = threadIdx.x >> 6;
    const int nw = blockDim.x >> 6;
    v = wred(v);
    if (lane == 0) sb[w] = v;
    __syncthreads();
    float r = 0.0f;
    if (threadIdx.x == 0) for (int i = 0; i < nw; ++i) r += sb[i];
    __syncthreads();
    return r;
}

// per-block redundant reduction of the per-wave slot arrays.
// Fills cnt_lds (min(count,REG)) if non-null. Returns the hard-mode flag.
__device__ bool derive_hard(const unsigned* __restrict__ ws, unsigned Kneg,
                            unsigned short* cnt_lds) {
    __shared__ unsigned rt[16], rm[16], ro[16];
    __shared__ unsigned flag;
    const int t = threadIdx.x, lane = t & 63, w = t >> 6;
    const int nw = blockDim.x >> 6;
    unsigned tot = 0u, mk = 0u, ov = 0u;
    for (unsigned i = t; i < NWAVES; i += blockDim.x) {
        unsigned cc = ws[OFF_CNT + i];
        unsigned c = cc & 0x7FFFFFFFu;
        tot += c; ov |= (cc >> 31); mk = max(mk, ws[OFF_MAXK + i]);
        if (cnt_lds) cnt_lds[i] = (unsigned short)(c < REG ? c : REG);
    }
    for (int o = 32; o; o >>= 1) {
        tot += (unsigned)__shfl_down((int)tot, o);
        mk = max(mk, (unsigned)__shfl_down((int)mk, o));
        ov |= (unsigned)__shfl_down((int)ov, o);
    }
    if (lane == 0) { rt[w] = tot; rm[w] = mk; ro[w] = ov; }
    __syncthreads();
    if (t == 0) {
        unsigned T = 0, M = 0, O = 0;
        for (int i = 0; i < nw; ++i) { T += rt[i]; M = max(M, rm[i]); O |= ro[i]; }
        flag = (T < Kneg) || O || (M >= FINE_LIMIT);
    }
    __syncthreads();
    return flag != 0u;
}

// descending rank-select over nparts partial hists; redundant per block.
// All NT threads call. First bin (from top) with cum >= R; r = R - above (>=1).
template<int NT>
__device__ void scan_desc(const unsigned* __restrict__ hist, int nparts,
                          int pstride, int nbins, unsigned R,
                          unsigned* bin_out, unsigned* r_out) {
    __shared__ unsigned sums[NT];
    __shared__ unsigned res[2];
    const int per = nbins / NT;          // <= 8
    const int t = threadIdx.x;
    unsigned local[8];
    unsigned s = 0;
    for (int j = 0; j < per; ++j) {
        const int bin = nbins - 1 - (t * per + j);
        unsigned v = 0;
        for (int p = 0; p < nparts; ++p) v += hist[p * pstride + bin];
        local[j] = v;
        s += v;
    }
    if (t == 0) { res[0] = 0u; res[1] = 1u; }
    sums[t] = s;
    __syncthreads();
    for (int off = 1; off < NT; off <<= 1) {
        unsigned v = (t >= off) ? sums[t - off] : 0u;
        __syncthreads();
        sums[t] += v;
        __syncthreads();
    }
    const unsigned incl = sums[t], excl = incl - s;
    if (excl < R && incl >= R) {
        unsigned cum = excl;
        for (int j = 0; j < per; ++j) {
            if (cum + local[j] >= R) {
                res[0] = (unsigned)(nbins - 1 - (t * per + j));
                res[1] = R - cum;
                break;
            }
            cum += local[j];
        }
    }
    __syncthreads();
    *bin_out = res[0];
    *r_out = res[1];
    __syncthreads();
}

// ---- k_main: pos_sum + per-wave-region compact. ZERO atomics. ----
__global__ __launch_bounds__(256)
void k_main(const float* __restrict__ x, const float* __restrict__ y,
            unsigned* __restrict__ ws, unsigned cap_words, int n) {
    const int tid = threadIdx.x;
    const int lane = tid & 63;
    const unsigned waveid = blockIdx.x * 4 + (tid >> 6);
    unsigned* cand = ws + OFF_CAND;
    const unsigned base = waveid * REG;

    // block 0: zero hist2 + histF2 (consumed by k_mid/k_fin after boundaries)
    if (blockIdx.x == 0)
        for (int i = tid; i < 2 * NB2; i += 256) ws[i] = 0u;

    float ps = 0.0f;
    unsigned kmax = 0u, cur = 0u, ovf = 0u;
    const int n4 = n >> 2;
    const float4* x4 = (const float4*)x;
    const float4* y4 = (const float4*)y;
    const unsigned gtid = blockIdx.x * blockDim.x + tid;
    const unsigned gstride = gridDim.x * blockDim.x;
    for (unsigned i = gtid; i < (unsigned)n4; i += gstride) {
        float4 xv = x4[i];
        float4 yv = y4[i];
        float xs[4] = {xv.x, xv.y, xv.z, xv.w};
        float ys[4] = {yv.x, yv.y, yv.z, yv.w};
#pragma unroll
        for (int c = 0; c < 4; ++c) {
            bool pos = ys[c] > 0.0f;
            if (pos) ps += softplusf(-xs[c]);
            unsigned k = f2key(xs[c]);
            bool cnd = (!pos) && (k >= K0);
            unsigned long long mask = __ballot(cnd);
            if (mask) {
                if (cnd) {
                    kmax = max(kmax, k);
                    unsigned slot = cur + (unsigned)__popcll(mask & ((1ull << lane) - 1ull));
                    unsigned gi = base + slot;
                    if (slot < REG && gi < cap_words) cand[gi] = k;
                    else ovf = 1u;
                }
                cur += (unsigned)__popcll(mask);
            }
        }
    }
    // tail (n % 4): wave 0 only; lane 0 participates whenever any lane does,
    // so lane 0's cur stays the wave count.
    if (waveid == 0) {
        for (int i = (n & ~3) + lane; i < n; i += 64) {
            float xs = x[i];
            bool pos = y[i] > 0.0f;
            if (pos) ps += softplusf(-xs);
            unsigned k = f2key(xs);
            bool cnd = (!pos) && (k >= K0);
            unsigned long long mask = __ballot(cnd);
            if (mask) {
                if (cnd) {
                    kmax = max(kmax, k);
                    unsigned slot = cur + (unsigned)__popcll(mask & ((1ull << lane) - 1ull));
                    unsigned gi = base + slot;
                    if (slot < REG && gi < cap_words) cand[gi] = k;
                    else ovf = 1u;
                }
                cur += (unsigned)__popcll(mask);
            }
        }
    }
    if (base + REG > cap_words) ovf = 1u;
    ps = wred(ps);
    kmax = wredmax(kmax);
    unsigned anyovf = (__ballot(ovf != 0u) != 0ull) ? 0x80000000u : 0u;
    if (lane == 0) {
        ws[OFF_CNT + waveid] = (cur & 0x7FFFFFFFu) | anyovf;
        ((float*)ws)[OFF_POSP + waveid] = ps;
        ws[OFF_MAXK + waveid] = kmax;
    }
}

// ---- k_hist (32 x 1024): private partial L1 histograms, pure stores ----
__global__ __launch_bounds__(1024)
void k_hist(const float* __restrict__ x, const float* __restrict__ y,
            unsigned* __restrict__ ws, const int* __restrict__ pos_num, int n) {
    __shared__ unsigned h[NB1];
    __shared__ unsigned short cnt[NWAVES];
    const int t = threadIdx.x;
    const unsigned Kneg = (unsigned)(pos_num[0] * 3);
    const bool hard = derive_hard(ws, Kneg, cnt);
    for (int i = t; i < NB1; i += 1024) h[i] = 0u;
    __syncthreads();
    const unsigned gtid = blockIdx.x * 1024 + t;
    const unsigned gstride = gridDim.x * 1024;
    if (!hard) {
        const unsigned* cand = ws + OFF_CAND;
        for (unsigned i = gtid; i < (unsigned)CANDW; i += gstride)
            if ((i & (REG - 1)) < (unsigned)cnt[i >> 8])
                atomicAdd(&h[(cand[i] - K0) >> 13], 1u);
    } else {
        for (unsigned i = gtid; i < (unsigned)n; i += gstride)
            if (y[i] == 0.0f) atomicAdd(&h[f2key(x[i]) >> 19], 1u);
    }
    __syncthreads();
    for (int i = t; i < NB1; i += 1024)
        ws[OFF_H1P + blockIdx.x * NB1 + i] = h[i];      // pure store
}

// ---- k_mid (32 x 1024): scan1; sure-sum; boundary bin -> hist2/histF2 ----
__global__ __launch_bounds__(1024)
void k_mid(const float* __restrict__ x, const float* __restrict__ y,
           unsigned* __restrict__ ws, const int* __restrict__ pos_num, int n) {
    __shared__ unsigned short cnt[NWAVES];
    Ctrl* c = (Ctrl*)ws;
    const unsigned Kneg = (unsigned)(pos_num[0] * 3);
    const bool hard = derive_hard(ws, Kneg, cnt);
    unsigned b1, r1;
    scan_desc<1024>(ws + OFF_H1P, NH, NB1, NB1, Kneg, &b1, &r1);
    const unsigned gtid = blockIdx.x * 1024 + threadIdx.x;
    const unsigned gstride = gridDim.x * 1024;
    float ss = 0.0f;
    if (!hard) {
        const unsigned* cand = ws + OFF_CAND;
        for (unsigned i = gtid; i < (unsigned)CANDW; i += gstride)
            if ((i & (REG - 1)) < (unsigned)cnt[i >> 8]) {
                unsigned kp = cand[i] - K0;
                unsigned b = kp >> 13;
                if (b > b1) ss += softplusf(key2f(kp + K0));
                else if (b == b1) {      // ~1.1K keys total: scattered atomics
                    unsigned l2 = kp & 0x1FFFu;
                    atomicAdd(&c->hist2[l2], 1u);
                    atomicAdd(&c->histF2[l2], softplusf(key2f(kp + K0)));
                }
            }
    } else {
        for (unsigned i = gtid; i < (unsigned)n; i += gstride)
            if (y[i] == 0.0f) {
                float xs = x[i];
                unsigned k = f2key(xs);
                unsigned b = k >> 19;
                if (b > b1) ss += softplusf(xs);
                else if (b == b1) atomicAdd(&c->hist2[(k >> 6) & 0x1FFFu], 1u);
            }
    }
    ss = bred(ss);
    if (threadIdx.x == 0) {
        ((float*)ws)[OFF_SURE + blockIdx.x] = ss;       // private slot
        if (blockIdx.x == 0) { c->b1 = b1; c->r1 = r1; }
    }
}

// ---- k_fin (1 x 1024): scan hist2; combine everything ----
__global__ __launch_bounds__(1024)
void k_fin(const float* __restrict__ x, const float* __restrict__ y,
           unsigned* __restrict__ ws, const int* __restrict__ pos_num,
           float* __restrict__ out, int n) {
    Ctrl* c = (Ctrl*)ws;
    const int t = threadIdx.x;
    const int p = pos_num[0];
    const unsigned Kneg = (unsigned)(p * 3);
    const bool hard = derive_hard(ws, Kneg, (unsigned short*)nullptr);
    const unsigned b1 = c->b1, r1 = c->r1;
    unsigned b2, r2;
    scan_desc<1024>(c->hist2, 1, 0, NB2, r1, &b2, &r2);
    float s = 0.0f;
    for (unsigned i = t; i < NWAVES; i += 1024) s += ((float*)ws)[OFF_POSP + i];
    if (t < NH) s += ((float*)ws)[OFF_SURE + t];
    if (!hard) {
        for (unsigned j = b2 + 1 + t; j < NB2; j += 1024) s += c->histF2[j];
        s = bred(s);
        if (t == 0) {
            unsigned H = K0 + ((b1 << 13) | b2);
            out[0] = (s + (float)r2 * softplusf(key2f(H))) / (float)(4 * p);
        }
    } else {
        // resolve last 6 bits by streaming x,y (correctness path; never taken
        // for this input). 64-bin LDS hist + float sums, then serial scan.
        __shared__ unsigned h64[64];
        __shared__ float f64[64];
        for (int i = t; i < 64; i += 1024) { h64[i] = 0u; f64[i] = 0.0f; }
        __syncthreads();
        float s2 = 0.0f;
        for (unsigned i = t; i < (unsigned)n; i += 1024)
            if (y[i] == 0.0f) {
                float xs = x[i];
                unsigned k = f2key(xs);
                if ((k >> 19) == b1) {
                    unsigned l2 = (k >> 6) & 0x1FFFu;
                    if (l2 > b2) s2 += softplusf(xs);
                    else if (l2 == b2) {
                        atomicAdd(&h64[k & 63u], 1u);
                        atomicAdd(&f64[k & 63u], softplusf(xs));
                    }
                }
            }
        __syncthreads();
        s = bred(s + s2);
        if (t == 0) {
            unsigned R = r2, c3 = 0, r3 = 1;
            float above = 0.0f;
            for (int j = 63; j >= 0; --j) {
                if (h64[j] >= R) { c3 = (unsigned)j; r3 = R; break; }
                R -= h64[j];
                above += f64[j];
            }
            unsigned H = (b1 << 19) | (b2 << 6) | c3;
            out[0] = (s + above + (float)r3 * softplusf(key2f(H))) / (float)(4 * p);
        }
    }
}

extern "C" void kernel_launch(void* const* d_in, const int* in_sizes, int n_in,
                              void* d_out, int out_size, void* d_ws, size_t ws_size,
                              hipStream_t stream) {
    const float* x = (const float*)d_in[0];
    const float* y = (const float*)d_in[1];
    const int* pos_num = (const int*)d_in[2];
    float* out = (float*)d_out;
    const int n = in_sizes[0];

    unsigned* ws = (unsigned*)d_ws;
    unsigned cap_words = 0u;
    if (ws_size / 4 > (size_t)OFF_CAND)
        cap_words = (unsigned)(ws_size / 4 - OFF_CAND);
    if (cap_words > (unsigned)CANDW) cap_words = (unsigned)CANDW;

    k_main<<<2048, 256, 0, stream>>>(x, y, ws, cap_words, n);
    k_hist<<<NH, 1024, 0, stream>>>(x, y, ws, pos_num, n);
    k_mid<<<NH, 1024, 0, stream>>>(x, y, ws, pos_num, n);
    k_fin<<<1, 1024, 0, stream>>>(x, y, ws, pos_num, out, n);
}

// Round 9
// 163.126 us; speedup vs baseline: 1.4523x; 1.4523x over previous
//
#include <hip/hip_runtime.h>
#include <math.h>

// OHNM loss: pos BCE sum + top-k(600000) negative softplus sum, mean over 800000.
//
// R9: 4 dispatches built from R7-proven components (R8 lesson: one pathological
// kernel from a big restructure; iterate on the proven shape).
//  k_main (2048x256): R7's zero-atomic pass: pos partial sums + per-WAVE
//    private cand regions (ballot cursor, plain stores, zero-filled padding).
//  k_h1 (64x1024): per-block partial hists over cand: counts AND float
//    softplus sums per bin (1024 bins: min((k-K0)>>13, 1023)). Pure stores.
//  k_h2 (64x1024): R7-shape scan of 64 partials -> (b1,r1); stream cand once,
//    stage boundary-bin keys (~2.8K total) in LDS, ONE global atomic/block to
//    side buffer; fold own partial's above-b1 fsums + pos slice into a slot.
//  k_fin (1x1024): sum 64 slots + exact 3-level (11/11/10-bit) LDS radix
//    select over side keys (full 32-bit keys -> clamp bin is safe; exact ties).
// hard mode (cand shortfall / region or staging overflow): k_fin runs the same
// generic select STREAMING x,y (1 block, slow, exact). Never taken here.

#define K0 0xBF800000u             // f2key(1.0f)
#define NWAVES 8192                // k_main: 2048 blocks x 4 waves
#define REG 256                    // cand words per wave (lambda=159)
#define NH 64                      // partial-hist blocks
#define NB 1024                    // L1 bins
#define LBUF 8192                  // k_h2 LDS staging (words)
#define SIDE_CAP_MAX (4u << 20)    // 4M keys (16 MB)

// ---- ws layout (word offsets) ----
#define OFF_SIDE_CNT 0
#define OFF_FLAGS    1
#define OFF_B1       2
#define OFF_R1       3
#define OFF_SLOT     64                       // 64 floats
#define OFF_CNT      128                      // 8192 per-wave counts (|ovf<<31)
#define OFF_POSP     (OFF_CNT + NWAVES)       // 8192 floats
#define OFF_HC       (OFF_POSP + NWAVES)      // 64 x 1024 counts
#define OFF_HF       (OFF_HC + NH * NB)       // 64 x 1024 floats
#define OFF_SIDE     (OFF_HF + NH * NB)       // side key buffer
#define OFF_CAND     (OFF_SIDE + SIDE_CAP_MAX)
#define CANDW        (NWAVES * REG)           // 2,097,152 words (8 MB)

__device__ __forceinline__ unsigned f2key(float x) {
    unsigned u = __float_as_uint(x);
    return (u & 0x80000000u) ? ~u : (u | 0x80000000u);
}
__device__ __forceinline__ float key2f(unsigned k) {
    unsigned u = (k & 0x80000000u) ? (k & 0x7FFFFFFFu) : ~k;
    return __uint_as_float(u);
}
__device__ __forceinline__ float softplusf(float x) {
    return fmaxf(x, 0.0f) + __logf(1.0f + __expf(-fabsf(x)));
}
__device__ __forceinline__ float wred(float v) {
    v += __shfl_down(v, 32); v += __shfl_down(v, 16); v += __shfl_down(v, 8);
    v += __shfl_down(v, 4);  v += __shfl_down(v, 2);  v += __shfl_down(v, 1);
    return v;
}
// block float-sum; result valid on thread 0
__device__ float bred(float v) {
    __shared__ float sb[16];
    const int lane = threadIdx.x & 63, w = threadIdx.x >> 6;
    const int nw = blockDim.x >> 6;
    v = wred(v);
    if (lane == 0) sb[w] = v;
    __syncthreads();
    float r = 0.0f;
    if (threadIdx.x == 0) for (int i = 0; i < nw; ++i) r += sb[i];
    __syncthreads();
    return r;
}

// hard flag: cand shortfall OR any wave-region overflow OR staging overflow.
// Per-block redundant, coalesced reads of the 8192-word count array. 1024 thr.
__device__ bool derive_hard(const unsigned* __restrict__ ws, unsigned Kneg) {
    __shared__ unsigned rt[16], ro[16];
    __shared__ unsigned flag;
    const int t = threadIdx.x, lane = t & 63, w = t >> 6;
    unsigned tot = 0u, ov = 0u;
    for (unsigned i = t; i < NWAVES; i += 1024) {
        unsigned cc = ws[OFF_CNT + i];
        tot += cc & 0x7FFFFFFFu;
        ov |= cc >> 31;
    }
    for (int o = 32; o; o >>= 1) {
        tot += (unsigned)__shfl_down((int)tot, o);
        ov |= (unsigned)__shfl_down((int)ov, o);
    }
    if (lane == 0) { rt[w] = tot; ro[w] = ov; }
    __syncthreads();
    if (t == 0) {
        unsigned T = 0, O = 0;
        for (int i = 0; i < 16; ++i) { T += rt[i]; O |= ro[i]; }
        flag = (T < Kneg) || O || ws[OFF_FLAGS];
    }
    __syncthreads();
    return flag != 0u;
}

// descending rank-select over the NH x NB global partial hists (per=1,
// coalesced: thread t owns bin 1023-t). 1024 threads. R >= 1.
__device__ void scanP(const unsigned* __restrict__ hp, unsigned R,
                      unsigned* b_out, unsigned* r_out) {
    __shared__ unsigned sums[1024];
    __shared__ unsigned res[2];
    const int t = threadIdx.x;
    const int bin = (NB - 1) - t;
    unsigned s = 0;
    for (int p = 0; p < NH; ++p) s += hp[p * NB + bin];
    if (t == 0) { res[0] = 0u; res[1] = 1u; }
    sums[t] = s;
    __syncthreads();
    for (int off = 1; off < 1024; off <<= 1) {
        unsigned v = (t >= off) ? sums[t - off] : 0u;
        __syncthreads();
        sums[t] += v;
        __syncthreads();
    }
    const unsigned incl = sums[t], excl = incl - s;
    if (excl < R && incl >= R) { res[0] = (unsigned)bin; res[1] = R - excl; }
    __syncthreads();
    *b_out = res[0];
    *r_out = res[1];
    __syncthreads();
}

// descending rank-select over an LDS hist (nbins 2048 or 1024) + fsum-above.
// b/r uniform; fa valid on thread 0 only. 1024 threads.
__device__ void scanL(const unsigned* __restrict__ cnt, const float* __restrict__ fsm,
                      int nbins, unsigned R,
                      unsigned* b_out, unsigned* r_out, float* fa_out) {
    __shared__ unsigned sums[1024];
    __shared__ unsigned res[2];
    __shared__ float sred;
    const int t = threadIdx.x;
    const int per = nbins >> 10;           // 1 or 2
    unsigned local[2];
    unsigned s = 0;
    for (int j = 0; j < per; ++j) {
        local[j] = cnt[nbins - 1 - (t * per + j)];
        s += local[j];
    }
    if (t == 0) { res[0] = 0u; res[1] = 1u; sred = 0.0f; }
    sums[t] = s;
    __syncthreads();
    for (int off = 1; off < 1024; off <<= 1) {
        unsigned v = (t >= off) ? sums[t - off] : 0u;
        __syncthreads();
        sums[t] += v;
        __syncthreads();
    }
    const unsigned incl = sums[t], excl = incl - s;
    if (excl < R && incl >= R) {
        unsigned cum = excl;
        for (int j = 0; j < per; ++j) {
            if (cum + local[j] >= R) {
                res[0] = (unsigned)(nbins - 1 - (t * per + j));
                res[1] = R - cum;
                break;
            }
            cum += local[j];
        }
    }
    __syncthreads();
    const unsigned b = res[0];
    float f = 0.0f;
    for (int j = (int)b + 1 + t; j < nbins; j += 1024) f += fsm[j];
    f = wred(f);
    if ((t & 63) == 0) atomicAdd(&sred, f);
    __syncthreads();
    *b_out = b;
    *r_out = res[1];
    if (t == 0) *fa_out = sred;
    __syncthreads();
}

// exact top-R softplus sum over a key source, by 3-level (11/11/10-bit) LDS
// radix select on the FULL 32-bit key. One block, 1024 threads.
// source: stream=false -> side[0..m3); stream=true -> negatives of x,y.
// Return value valid on thread 0 only.
__device__ float select_block(const unsigned* __restrict__ side, unsigned m3,
                              const float* __restrict__ x, const float* __restrict__ y,
                              int n, bool stream, unsigned R) {
    __shared__ unsigned cnt[2048];
    __shared__ float fsm[2048];
    const int t = threadIdx.x;
    unsigned prefix = 0u, mask = 0u;
    float above = 0.0f;                    // thread 0 only
    const int sh[3] = {21, 10, 0};
    const int nb[3] = {2048, 2048, 1024};
    for (int l = 0; l < 3; ++l) {
        for (int i = t; i < nb[l]; i += 1024) { cnt[i] = 0u; fsm[i] = 0.0f; }
        __syncthreads();
        if (!stream) {
            for (unsigned i = t; i < m3; i += 1024) {
                unsigned k = side[i];
                if ((k & mask) == prefix) {
                    unsigned b = (k >> sh[l]) & (unsigned)(nb[l] - 1);
                    atomicAdd(&cnt[b], 1u);
                    atomicAdd(&fsm[b], softplusf(key2f(k)));
                }
            }
        } else {
            for (unsigned i = t; i < (unsigned)n; i += 1024) {
                if (y[i] == 0.0f) {
                    unsigned k = f2key(x[i]);
                    if ((k & mask) == prefix) {
                        unsigned b = (k >> sh[l]) & (unsigned)(nb[l] - 1);
                        atomicAdd(&cnt[b], 1u);
                        atomicAdd(&fsm[b], softplusf(key2f(k)));
                    }
                }
            }
        }
        __syncthreads();
        unsigned b, r;
        float fa;
        scanL(cnt, fsm, nb[l], R, &b, &r, &fa);
        if (t == 0) above += fa;
        R = r;
        prefix |= b << sh[l];
        mask |= (unsigned)(nb[l] - 1) << sh[l];
        __syncthreads();
    }
    // prefix is the exact k-th key value; R = tie copies included
    return above + (float)R * softplusf(key2f(prefix));
}

// ---- k_main: pos partial sums + per-wave-region compact. ZERO atomics. ----
__global__ __launch_bounds__(256)
void k_main(const float* __restrict__ x, const float* __restrict__ y,
            unsigned* __restrict__ ws, unsigned cap_words, int n) {
    const int tid = threadIdx.x;
    const int lane = tid & 63;
    const unsigned waveid = blockIdx.x * 4 + (tid >> 6);
    unsigned* cand = ws + OFF_CAND;
    const unsigned base = waveid * REG;

    if (blockIdx.x == 0)                      // zero control words + slots
        for (int i = tid; i < 128; i += 256) ws[i] = 0u;

    float ps = 0.0f;
    unsigned cur = 0u, ovf = 0u;
    const int n4 = n >> 2;
    const float4* x4 = (const float4*)x;
    const float4* y4 = (const float4*)y;
    const unsigned gtid = blockIdx.x * blockDim.x + tid;
    const unsigned gstride = gridDim.x * blockDim.x;
    for (unsigned i = gtid; i < (unsigned)n4; i += gstride) {
        float4 xv = x4[i];
        float4 yv = y4[i];
        float xs[4] = {xv.x, xv.y, xv.z, xv.w};
        float ys[4] = {yv.x, yv.y, yv.z, yv.w};
#pragma unroll
        for (int c = 0; c < 4; ++c) {
            bool pos = ys[c] > 0.0f;
            if (pos) ps += softplusf(-xs[c]);
            unsigned k = f2key(xs[c]);
            bool cnd = (!pos) && (k >= K0);
            unsigned long long mask = __ballot(cnd);
            if (mask) {
                if (cnd) {
                    unsigned slot = cur + (unsigned)__popcll(mask & ((1ull << lane) - 1ull));
                    unsigned gi = base + slot;
                    if (slot < REG && gi < cap_words) cand[gi] = k;
                    else ovf = 1u;
                }
                cur += (unsigned)__popcll(mask);
            }
        }
    }
    // tail (n % 4): wave 0 only; ballot keeps cur wave-uniform
    if (waveid == 0) {
        for (int i = (n & ~3) + lane; i < n; i += 64) {
            float xs = x[i];
            bool pos = y[i] > 0.0f;
            if (pos) ps += softplusf(-xs);
            unsigned k = f2key(xs);
            bool cnd = (!pos) && (k >= K0);
            unsigned long long mask = __ballot(cnd);
            if (mask) {
                if (cnd) {
                    unsigned slot = cur + (unsigned)__popcll(mask & ((1ull << lane) - 1ull));
                    unsigned gi = base + slot;
                    if (slot < REG && gi < cap_words) cand[gi] = k;
                    else ovf = 1u;
                }
                cur += (unsigned)__popcll(mask);
            }
        }
    }
    // zero-fill padding (stage kernels skip k < K0; 0 < K0)
    for (unsigned j = cur + lane; j < REG; j += 64) {
        unsigned gi = base + j;
        if (gi < cap_words) cand[gi] = 0u;
    }
    if (base + REG > cap_words) ovf = 1u;
    ps = wred(ps);
    unsigned anyovf = (__ballot(ovf != 0u) != 0ull) ? 0x80000000u : 0u;
    if (lane == 0) {
        ws[OFF_CNT + waveid] = (cur & 0x7FFFFFFFu) | anyovf;
        ((float*)ws)[OFF_POSP + waveid] = ps;
    }
}

// ---- k_h1 (64x1024): partial count+fsum hists over cand. Pure stores. ----
__global__ __launch_bounds__(1024)
void k_h1(unsigned* __restrict__ ws, const int* __restrict__ pos_num,
          unsigned cap_words) {
    __shared__ unsigned hc[NB];
    __shared__ float hf[NB];
    const int t = threadIdx.x;
    const unsigned Kneg = (unsigned)(pos_num[0] * 3);
    if (derive_hard(ws, Kneg)) return;        // k_fin streams in hard mode
    if (t < NB) { hc[t] = 0u; hf[t] = 0.0f; }
    __syncthreads();
    const unsigned* cand = ws + OFF_CAND;
    const unsigned lim = (unsigned)CANDW < cap_words ? (unsigned)CANDW : cap_words;
    const unsigned gtid = blockIdx.x * 1024 + t;
    const unsigned gstride = gridDim.x * 1024;
    for (unsigned i = gtid; i < lim; i += gstride) {
        unsigned k = cand[i];
        if (k >= K0) {
            unsigned b = (k - K0) >> 13;
            b = b > (NB - 1) ? (NB - 1) : b;  // clamp: x >= 2 (full keys later)
            atomicAdd(&hc[b], 1u);
            atomicAdd(&hf[b], softplusf(key2f(k)));
        }
    }
    __syncthreads();
    if (t < NB) {
        ws[OFF_HC + blockIdx.x * NB + t] = hc[t];
        ((float*)ws)[OFF_HF + blockIdx.x * NB + t] = hf[t];
    }
}

// ---- k_h2 (64x1024): scan1 -> (b1,r1); stage boundary keys; fold slot. ----
__global__ __launch_bounds__(1024)
void k_h2(unsigned* __restrict__ ws, const int* __restrict__ pos_num,
          unsigned cap_words, unsigned side_cap) {
    __shared__ unsigned lbuf[LBUF];
    __shared__ unsigned lcnt, gbase;
    const int t = threadIdx.x;
    const unsigned Kneg = (unsigned)(pos_num[0] * 3);
    if (derive_hard(ws, Kneg)) return;
    unsigned b1, r1;
    scanP(ws + OFF_HC, Kneg, &b1, &r1);
    if (t == 0) lcnt = 0u;
    __syncthreads();
    const unsigned* cand = ws + OFF_CAND;
    unsigned* side = ws + OFF_SIDE;
    const unsigned lim = (unsigned)CANDW < cap_words ? (unsigned)CANDW : cap_words;
    const unsigned gtid = blockIdx.x * 1024 + t;
    const unsigned gstride = gridDim.x * 1024;
    for (unsigned i = gtid; i < lim; i += gstride) {
        unsigned k = cand[i];
        if (k >= K0) {
            unsigned b = (k - K0) >> 13;
            b = b > (NB - 1) ? (NB - 1) : b;
            if (b == b1) {                    // ~44 hits/block: LDS atomic fine
                unsigned p = atomicAdd(&lcnt, 1u);
                if (p < LBUF) lbuf[p] = k;
            }
        }
    }
    __syncthreads();
    const unsigned m = lcnt < LBUF ? lcnt : LBUF;
    if (t == 0) {
        gbase = atomicAdd(&ws[OFF_SIDE_CNT], m);   // ONE per block
        if (lcnt > LBUF) atomicOr(&ws[OFF_FLAGS], 1u);
    }
    __syncthreads();
    unsigned oob = 0u;
    for (unsigned i = t; i < m; i += 1024) {
        unsigned gi = gbase + i;
        if (gi < side_cap) side[gi] = lbuf[i];
        else oob = 1u;
    }
    if (oob) atomicOr(&ws[OFF_FLAGS], 1u);
    // slot: this block's pos-partial slice + own partial's fsums above b1
    float s = 0.0f;
    if (t < NWAVES / NH) s += ((float*)ws)[OFF_POSP + blockIdx.x * (NWAVES / NH) + t];
    if ((unsigned)t > b1) s += ((float*)ws)[OFF_HF + blockIdx.x * NB + t];
    s = bred(s);
    if (t == 0) {
        ((float*)ws)[OFF_SLOT + blockIdx.x] = s;
        if (blockIdx.x == 0) { ws[OFF_B1] = b1; ws[OFF_R1] = r1; }
    }
}

// ---- k_fin (1x1024): slots + exact select over side keys (or stream). ----
__global__ __launch_bounds__(1024)
void k_fin(const float* __restrict__ x, const float* __restrict__ y,
           unsigned* __restrict__ ws, const int* __restrict__ pos_num,
           float* __restrict__ out, int n, unsigned side_cap) {
    const int t = threadIdx.x;
    const int p = pos_num[0];
    const unsigned Kneg = (unsigned)(p * 3);
    const bool hard = derive_hard(ws, Kneg);
    float total;
    if (!hard) {
        float base = 0.0f;
        if (t < NH) base = ((float*)ws)[OFF_SLOT + t];
        base = bred(base);
        unsigned m3 = ws[OFF_SIDE_CNT];
        if (m3 > side_cap) m3 = side_cap;
        float sel = select_block(ws + OFF_SIDE, m3, x, y, n, false, ws[OFF_R1]);
        total = base + sel;                  // thread 0
    } else {
        float ps = 0.0f;
        for (unsigned i = t; i < NWAVES; i += 1024) ps += ((float*)ws)[OFF_POSP + i];
        ps = bred(ps);
        float sel = select_block(nullptr, 0u, x, y, n, true, Kneg);
        total = ps + sel;                    // thread 0
    }
    if (t == 0) out[0] = total / (float)(4 * p);
}

extern "C" void kernel_launch(void* const* d_in, const int* in_sizes, int n_in,
                              void* d_out, int out_size, void* d_ws, size_t ws_size,
                              hipStream_t stream) {
    const float* x = (const float*)d_in[0];
    const float* y = (const float*)d_in[1];
    const int* pos_num = (const int*)d_in[2];
    float* out = (float*)d_out;
    const int n = in_sizes[0];

    unsigned* ws = (unsigned*)d_ws;
    const size_t wsw = ws_size / 4;
    unsigned cap_words = 0u;
    if (wsw > (size_t)OFF_CAND) cap_words = (unsigned)(wsw - OFF_CAND);
    if (cap_words > (unsigned)CANDW) cap_words = (unsigned)CANDW;
    unsigned side_cap = 0u;
    if (wsw > (size_t)OFF_SIDE) side_cap = (unsigned)(wsw - OFF_SIDE);
    if (side_cap > SIDE_CAP_MAX) side_cap = SIDE_CAP_MAX;

    k_main<<<2048, 256, 0, stream>>>(x, y, ws, cap_words, n);
    k_h1<<<NH, 1024, 0, stream>>>(ws, pos_num, cap_words);
    k_h2<<<NH, 1024, 0, stream>>>(ws, pos_num, cap_words, side_cap);
    k_fin<<<1, 1024, 0, stream>>>(x, y, ws, pos_num, out, n, side_cap);
}